// Round 8
// baseline (55.607 us; speedup 1.0000x reference)
//
#include <hip/hip_runtime.h>
#include <stdint.h>

typedef __attribute__((ext_vector_type(4))) float  f32x4;
typedef __attribute__((ext_vector_type(8))) __bf16 bf16x8;

#define NB   32
#define CC   512
#define DD   512
#define HW   1024
#define BM   128     // rows per block
#define BN   512     // cols per block (64 per wave)
#define BK   32
#define NKS  16

#define WAITL()  asm volatile("s_waitcnt lgkmcnt(0)" ::: "memory")
#define BARR()   do { asm volatile("" ::: "memory"); __builtin_amdgcn_s_barrier(); \
                      asm volatile("" ::: "memory"); } while (0)

// Fused softmax + batched GEMM: out[n] = softmax(atts[n]) @ images[n]
//   grid 256 = 32 batches x 4 row-tiles x 2 col-tiles, XCD-affine (n%8 = b%8)
//   block 512 thr / 8 waves; wave tile 128x64 (acc[8][4])
//   phase 0: softmax stats (m, 1/sum) for the block's 128 rows
//   K-loop:  A = exp(atts-m)*inv regenerated on the fly -> lA dbuf (pad-40)
//            B = images fp32 -> cvt bf16 -> wave-PRIVATE LDS dbuf
//            one raw s_barrier + lgkmcnt(0) per step; NO vmcnt drains
__global__ __launch_bounds__(512, 2) void fused_kernel(
        const float* __restrict__ images, const float* __restrict__ atts,
        float* __restrict__ out) {
    __shared__ unsigned short lA[2][BM][40];        // 20KB, pad-40 = bank-safe
    __shared__ unsigned short lB[8][2][4][64][8];   // 64KB, wave-private dbuf
    __shared__ float2 lStats[BM];                   // 1KB

    const int b  = blockIdx.x;       // 0..255
    const int g  = b & 7;            // XCD
    const int q  = b >> 3;           // 0..31
    const int n  = (q & 3) * 8 + g;  // batch, n%8 == XCD
    const int rt = (q >> 2) & 3;     // row tile 0..3
    const int ct = q >> 4;           // col tile 0..1

    const int r0 = rt * BM;
    const int c0 = ct * BN;

    const int tid  = threadIdx.x;
    const int lane = tid & 63;
    const int w    = tid >> 6;       // wave 0..7 -> cols c0 + w*64
    const int r15  = lane & 15;
    const int kgl  = lane >> 4;

    const float* gAt = atts + (size_t)n * CC * DD + (size_t)r0 * DD;
    const float* gB  = images + (size_t)n * DD * HW + c0 + w * 64;
    float*       gO  = out + (size_t)n * CC * HW + (size_t)r0 * HW + c0 + w * 64;

    // ---- phase 0: softmax stats, 16 rows per wave ----
    for (int rr = 0; rr < 16; ++rr) {
        const int row = w * 16 + rr;
        const float* a = gAt + (size_t)row * DD + lane * 8;
        f32x4 v0 = *(const f32x4*)a;
        f32x4 v1 = *(const f32x4*)(a + 4);
        float e[8] = {v0[0], v0[1], v0[2], v0[3], v1[0], v1[1], v1[2], v1[3]};
        float m = e[0];
        #pragma unroll
        for (int j = 1; j < 8; ++j) m = fmaxf(m, e[j]);
        #pragma unroll
        for (int s = 1; s < 64; s <<= 1) m = fmaxf(m, __shfl_xor(m, s, 64));
        float sum = 0.f;
        #pragma unroll
        for (int j = 0; j < 8; ++j) sum += __expf(e[j] - m);
        #pragma unroll
        for (int s = 1; s < 64; s <<= 1) sum += __shfl_xor(sum, s, 64);
        if (lane == 0) lStats[row] = make_float2(m, 1.0f / sum);
    }
    WAITL();
    BARR();

    // per-thread A-staging coords: row fixed for the whole kernel
    const int arow = tid >> 2;       // 0..127
    const int akg  = tid & 3;        // 16B slot within 32-k step
    const float2 st = lStats[arow];  // (row max, 1/sum)

    f32x4  acc[8][4] = {};
    f32x4  breg[8];

    auto stage_a = [&](int buf, int kt) {
        const float* p = gAt + (size_t)arow * DD + kt * BK + akg * 8;
        f32x4 u0 = *(const f32x4*)p;
        f32x4 u1 = *(const f32x4*)(p + 4);
        bf16x8 wv;
        #pragma unroll
        for (int j = 0; j < 4; ++j) {
            wv[j]     = (__bf16)(__expf(u0[j] - st.x) * st.y);
            wv[4 + j] = (__bf16)(__expf(u1[j] - st.x) * st.y);
        }
        *(bf16x8*)&lA[buf][arow][akg * 8] = wv;
    };
    auto load_b = [&](int kt) {
        const float* p = gB + (size_t)(kt * BK + kgl * 8) * HW + r15 * 4;
        #pragma unroll
        for (int j = 0; j < 8; ++j)
            breg[j] = *(const f32x4*)(p + (size_t)j * HW);
    };
    auto write_b = [&](int buf) {                   // compiler waits breg vmcnt
        #pragma unroll
        for (int cc = 0; cc < 4; ++cc) {
            bf16x8 wv;
            #pragma unroll
            for (int j = 0; j < 8; ++j) wv[j] = (__bf16)breg[j][cc];
            const int c  = r15 * 4 + cc;
            const int cs = c ^ ((c >> 3) & 3);
            *(bf16x8*)&lB[w][buf][kgl][cs][0] = wv;
        }
    };
    auto compute = [&](int abuf, int bbuf) {
        bf16x8 af[8], bv[4];
        #pragma unroll
        for (int m = 0; m < 8; ++m)
            af[m] = *(const bf16x8*)&lA[abuf][m * 16 + r15][kgl * 8];
        #pragma unroll
        for (int nf = 0; nf < 4; ++nf) {
            const int c  = nf * 16 + r15;
            const int cs = c ^ ((c >> 3) & 3);
            bv[nf] = *(const bf16x8*)&lB[w][bbuf][kgl][cs][0];
        }
        #pragma unroll
        for (int m = 0; m < 8; ++m)
            #pragma unroll
            for (int nf = 0; nf < 4; ++nf)
                acc[m][nf] = __builtin_amdgcn_mfma_f32_16x16x32_bf16(
                    af[m], bv[nf], acc[m][nf], 0, 0, 0);
    };

    // ---- prologue: stage tile 0 ----
    load_b(0);
    stage_a(0, 0);
    write_b(0);
    WAITL();
    BARR();

    // ---- K-loop: one barrier per step, no vmcnt drains ----
    for (int kt = 0; kt < NKS; ++kt) {
        const int cur = kt & 1, nxt = cur ^ 1;
        if (kt + 1 < NKS) {
            load_b(kt + 1);          // issue B early (used at write_b below)
            stage_a(nxt, kt + 1);    // atts L2-hit + exp + ds_write
        }
        compute(cur, cur);
        if (kt + 1 < NKS) write_b(nxt);
        WAITL();                     // ds_writes of nxt complete
        BARR();
    }

    // ---- epilogue: C/D layout col=lane&15, row=(lane>>4)*4+r ----
    #pragma unroll
    for (int m = 0; m < 8; ++m)
        #pragma unroll
        for (int nf = 0; nf < 4; ++nf)
            #pragma unroll
            for (int r = 0; r < 4; ++r) {
                const int row = m * 16 + kgl * 4 + r;
                const int col = nf * 16 + r15;
                gO[(size_t)row * HW + col] = acc[m][nf][r];
            }
}

extern "C" void kernel_launch(void* const* d_in, const int* in_sizes, int n_in,
                              void* d_out, int out_size, void* d_ws, size_t ws_size,
                              hipStream_t stream) {
    const float* images = (const float*)d_in[0];
    const float* atts   = (const float*)d_in[1];
    float*       out    = (float*)d_out;

    fused_kernel<<<dim3(NB * 8), dim3(512), 0, stream>>>(images, atts, out);
}

// Round 9
// 40.076 us; speedup vs baseline: 1.3875x; 1.3875x over previous
//
#include <hip/hip_runtime.h>
#include <stdint.h>

typedef __attribute__((ext_vector_type(4))) float  f32x4;
typedef __attribute__((ext_vector_type(8))) __bf16 bf16x8;

#define NB   32
#define CC   512
#define DD   512
#define HW   1024
#define NKS  16      // K-steps of 32

#define WAITL()  asm volatile("s_waitcnt lgkmcnt(0)" ::: "memory")
#define BARR()   do { asm volatile("" ::: "memory"); __builtin_amdgcn_s_barrier(); \
                      asm volatile("" ::: "memory"); } while (0)

// Fused softmax + batched GEMM: out[n] = softmax(atts[n]) @ images[n]
//   grid 256 = 32 batches x 4 row-tiles x 2 col-tiles, XCD-affine (n%8 = b%8)
//   block 512 thr / 8 waves; block tile 128 rows x 512 cols; wave: 128x64.
//   Phase 1 (once): read atts panel ONCE, softmax in f32, store normalized
//     bf16 A panel (128x512 = 128KB) in LDS, XOR-swizzled. No W in global.
//   Phase 2: BARRIER-FREE K-loop (A read-only; B staging is 16-lane-group
//     private) -> waves drift, loads issue continuously (R6's 3.58 TB/s
//     mechanism) with L2-friendly footprint (W gone, images via XCD L2).
__global__ __launch_bounds__(512, 2) void fused_kernel(
        const float* __restrict__ images, const float* __restrict__ atts,
        float* __restrict__ out) {
    __shared__ unsigned short lA[128][512];         // 128KB  [row][slot^row&7]
    __shared__ unsigned short lB[8][4][64][8];      // 32KB   wave/kgl-private

    const int b  = blockIdx.x;       // 0..255
    const int g  = b & 7;            // XCD
    const int q  = b >> 3;           // 0..31
    const int n  = (q & 3) * 8 + g;  // batch, n%8 == XCD
    const int t  = q >> 2;           // 0..7
    const int rt = t & 3;            // row tile 0..3 (128 rows)
    const int ct = t >> 2;           // col tile 0..1 (512 cols)

    const int tid  = threadIdx.x;
    const int lane = tid & 63;
    const int w    = tid >> 6;       // wave 0..7 -> cols ct*512 + w*64
    const int r15  = lane & 15;
    const int kgl  = lane >> 4;

    const float* gAt = atts + (size_t)n * CC * DD + (size_t)(rt * 128) * DD;
    const float* gB  = images + (size_t)n * DD * HW + ct * 512 + w * 64;
    float*       gO  = out + (size_t)n * CC * HW + (size_t)(rt * 128) * HW
                           + ct * 512 + w * 64;

    // ---- phase 1: softmax fill. 32 groups of 16 lanes; 4 rows each ----
    {
        const int grp = tid >> 4;    // 0..31
        const int l16 = tid & 15;
        for (int s = 0; s < 4; ++s) {
            const int row = grp * 4 + s;             // 0..127
            const float* ap = gAt + (size_t)row * DD + l16 * 32;
            f32x4 v[8];
            #pragma unroll
            for (int j = 0; j < 8; ++j) v[j] = *(const f32x4*)(ap + j * 4);
            float m = v[0][0];
            #pragma unroll
            for (int j = 0; j < 8; ++j)
                #pragma unroll
                for (int c = 0; c < 4; ++c) m = fmaxf(m, v[j][c]);
            #pragma unroll
            for (int k = 1; k < 16; k <<= 1) m = fmaxf(m, __shfl_xor(m, k, 16));
            float sum = 0.f;
            #pragma unroll
            for (int j = 0; j < 8; ++j)
                #pragma unroll
                for (int c = 0; c < 4; ++c) {
                    v[j][c] = __expf(v[j][c] - m);
                    sum += v[j][c];
                }
            #pragma unroll
            for (int k = 1; k < 16; k <<= 1) sum += __shfl_xor(sum, k, 16);
            const float inv = 1.0f / sum;
            #pragma unroll
            for (int p = 0; p < 4; ++p) {            // 4 bf16x8 slots per lane
                bf16x8 wv;
                #pragma unroll
                for (int e = 0; e < 8; ++e)
                    wv[e] = (__bf16)(v[p * 2 + (e >> 2)][e & 3] * inv);
                const int slot = (l16 * 4 + p) ^ (row & 7);
                *(bf16x8*)&lA[row][slot * 8] = wv;
            }
        }
    }
    WAITL();
    BARR();                          // the ONLY barrier in the kernel

    f32x4  acc[8][4] = {};
    f32x4  breg[8];

    // B: lane (kgl,r15) loads rows kt*32+kgl*8+j, cols r15*4..+3
    auto load_b = [&](int kt) {
        const float* p = gB + (size_t)(kt * 32 + kgl * 8) * HW + r15 * 4;
        #pragma unroll
        for (int j = 0; j < 8; ++j)
            breg[j] = *(const f32x4*)(p + (size_t)j * HW);
    };
    // cvt + 16-lane-group-private LDS transpose write (col-XOR, 2-way banks)
    auto write_b = [&]() {
        #pragma unroll
        for (int cc = 0; cc < 4; ++cc) {
            bf16x8 wv;
            #pragma unroll
            for (int j = 0; j < 8; ++j) wv[j] = (__bf16)breg[j][cc];
            const int c  = r15 * 4 + cc;
            const int cs = c ^ ((c >> 3) & 3);
            *(bf16x8*)&lB[w][kgl][cs][0] = wv;
        }
    };
    auto compute = [&](int kt) {
        bf16x8 af[8], bv[4];
        #pragma unroll
        for (int m = 0; m < 8; ++m) {
            const int row  = m * 16 + r15;
            const int slot = ((kt << 2) + kgl) ^ (r15 & 7);
            af[m] = *(const bf16x8*)&lA[row][slot * 8];
        }
        #pragma unroll
        for (int nf = 0; nf < 4; ++nf) {
            const int c  = nf * 16 + r15;
            const int cs = c ^ ((c >> 3) & 3);
            bv[nf] = *(const bf16x8*)&lB[w][kgl][cs][0];
        }
        #pragma unroll
        for (int m = 0; m < 8; ++m)
            #pragma unroll
            for (int nf = 0; nf < 4; ++nf)
                acc[m][nf] = __builtin_amdgcn_mfma_f32_16x16x32_bf16(
                    af[m], bv[nf], acc[m][nf], 0, 0, 0);
    };

    // ---- phase 2: barrier-free K-loop ----
    load_b(0);
    write_b();                       // compiler inserts breg vmcnt wait
    for (int kt = 0; kt < NKS; ++kt) {
        if (kt + 1 < NKS) load_b(kt + 1);   // issue early, no barrier in the way
        compute(kt);                 // bv reads (kt) ordered before next write
        if (kt + 1 < NKS) write_b(); // consumes breg(kt+1)
    }

    // ---- epilogue: C/D layout col=lane&15, row=(lane>>4)*4+r ----
    #pragma unroll
    for (int m = 0; m < 8; ++m)
        #pragma unroll
        for (int nf = 0; nf < 4; ++nf)
            #pragma unroll
            for (int r = 0; r < 4; ++r) {
                const int row = m * 16 + kgl * 4 + r;
                const int col = nf * 16 + r15;
                gO[(size_t)row * HW + col] = acc[m][nf][r];
            }
}

extern "C" void kernel_launch(void* const* d_in, const int* in_sizes, int n_in,
                              void* d_out, int out_size, void* d_ws, size_t ws_size,
                              hipStream_t stream) {
    const float* images = (const float*)d_in[0];
    const float* atts   = (const float*)d_in[1];
    float*       out    = (float*)d_out;

    fused_kernel<<<dim3(NB * 8), dim3(512), 0, stream>>>(images, atts, out);
}